// Round 4
// baseline (27.655 us; speedup 1.0000x reference)
//
#include <hip/hip_runtime.h>
#include <hip/hip_bf16.h>
#include <hip/hip_fp16.h>

// Graph3DBias: B=8, N=256, K=128, EMBED=768
// S[b,i,k] = sum_j mask_j * c_k * exp(-0.5*((y_bij-m_k)/s_k)^2),  y = mul*dist+bias
// out      = mask_i * (S @ W^T + b)
// Strategy: gaussians via 192-row fp16 lookup table (kills v_exp from hot loop),
// fp16 MFMA for the projection GEMM.

#define NN 256
#define KK 128
#define DD 768
#define RT 192                  // table rows
#define Y_LO (-2.0f)
#define IH (190.0f/22.0f)       // rows per unit y
#define HSTEP (22.0f/190.0f)    // y step per row

typedef _Float16 half8  __attribute__((ext_vector_type(8)));
typedef _Float16 half4v __attribute__((ext_vector_type(4)));
typedef _Float16 half2v __attribute__((ext_vector_type(2)));
typedef float    f32x4  __attribute__((ext_vector_type(4)));

// ---------- prep: bid<96 builds gaussian table G[192][128]; bid>=96 cvt W ----
__global__ __launch_bounds__(256) void k_prep(
    const float* __restrict__ means, const float* __restrict__ stds,
    const float* __restrict__ proj_w,
    _Float16* __restrict__ Gg, _Float16* __restrict__ Wh)
{
    const int bid = blockIdx.x, t = threadIdx.x;
    if (bid < 96) {
        const int el = bid*256 + t;           // 24576 = 192*128
        const int r = el >> 7, k = el & 127;
        const float m   = means[k];
        const float s   = fabsf(stds[k]) + 0.8f;
        const float inv = 1.0f / s;
        const float w   = inv * 0.84932160f;  // sqrt(0.5*log2e)
        const float nm  = -m * w;
        const float c   = inv * 0.39894253f;  // 1/sqrt(2*3.14159)
        const float y   = Y_LO + r * HSTEP;
        const float d   = fmaf(y, w, nm);
        Gg[r*KK + k] = (_Float16)(c * __builtin_amdgcn_exp2f(-(d*d)));
    } else {
        const int i = ((bid - 96)*256 + t) * 4;   // 98304 W elements
        float4 v = *(const float4*)(proj_w + i);
        half4v h;
        h.x=(_Float16)v.x; h.y=(_Float16)v.y; h.z=(_Float16)v.z; h.w=(_Float16)v.w;
        *(half4v*)(Wh + i) = h;
    }
}

// ---------- k_edges: 1024 blocks x 512 thr; 2 output rows per block ----------
__global__ __launch_bounds__(512) void k_edges(
    const float* __restrict__ pos,     // (B,N,3)
    const int*   __restrict__ xatom,   // (B,N)
    const float* __restrict__ mul_w,   // (1536)
    const float* __restrict__ bias_w,  // (1536)
    const _Float16* __restrict__ Gg,   // (192,128) table
    _Float16* __restrict__ Sh)         // (B*N, K)
{
    __shared__ __align__(16) _Float16 Gt[RT*KK];     // 48 KB
    __shared__ __align__(16) uint2  meta[2][NN];     // 4 KB  {row_byteoff, half2(f,f)}
    __shared__ __align__(16) float2 part[2][4][64];  // 4 KB

    const int bid = blockIdx.x;          // 1024
    const int t   = threadIdx.x;
    const int i0  = bid * 2;             // first global row
    const int b   = i0 >> 8;
    const int base = b << 8;

    // stage table into LDS (3072 uint4, coalesced)
    {
        const uint4* src = (const uint4*)Gg;
        uint4*       dst = (uint4*)Gt;
        #pragma unroll
        for (int it = 0; it < 6; ++it) dst[t + it*512] = src[t + it*512];
    }

    // meta phase: thread -> (row = t>>8, j = t&255)
    {
        const int row = t >> 8, j = t & 255;
        const int gi  = i0 + row;
        const int ai  = xatom[gi];
        const float pix = pos[gi*3+0], piy = pos[gi*3+1], piz = pos[gi*3+2];
        const int aj  = xatom[base + j];
        const float dx = pix - pos[(base+j)*3+0];
        const float dy = piy - pos[(base+j)*3+1];
        const float dz = piz - pos[(base+j)*3+2];
        const float dist = __builtin_amdgcn_sqrtf(dx*dx + dy*dy + dz*dz);
        const int idx = ai*128 + aj;
        float y = mul_w[idx]*dist + bias_w[idx];
        if (aj == 0) y = 1e20f;          // pad -> clamps to top rows (~0)
        float v = (y - Y_LO) * IH;
        v = fminf(fmaxf(v, 0.0f), 190.0f);
        const unsigned r = (unsigned)v;
        const float    f = v - (float)r;
        half2v fh; fh.x = (_Float16)f; fh.y = fh.x;
        uint2 mt;
        mt.x = r << 8;                   // byte offset of table row (128*2B)
        mt.y = __builtin_bit_cast(unsigned, fh);
        meta[row][j] = mt;
    }
    __syncthreads();

    // main loop: thread -> (row = t>>8, kp = t&63 covers k=2kp,2kp+1, jq = quarter)
    {
        const int row = t >> 8;
        const int kp  = t & 63;
        const int jq  = (t >> 6) & 3;
        const char*  gtb  = (const char*)Gt + kp*4;
        const uint2* mrow = &meta[row][jq*64];

        float accx = 0.f, accy = 0.f;
        #pragma unroll
        for (int jg = 0; jg < 8; ++jg) {
            half2v acc2 = (half2v)(_Float16)0.f;   // fp16 tree-acc over 8 terms
            #pragma unroll
            for (int jj = 0; jj < 8; ++jj) {
                uint2 mt = mrow[jg*8 + jj];        // broadcast (wave-uniform)
                const char* p = gtb + mt.x;
                unsigned lo = *(const unsigned*)p;          // G[r][2kp..2kp+1]
                unsigned hi = *(const unsigned*)(p + 256);  // G[r+1][...]
                half2v l  = __builtin_bit_cast(half2v, lo);
                half2v h  = __builtin_bit_cast(half2v, hi);
                half2v f2 = __builtin_bit_cast(half2v, mt.y);
                acc2 += l + f2*(h - l);            // v_pk_sub/fma/add
            }
            accx += (float)acc2.x;
            accy += (float)acc2.y;
        }
        part[row][jq][kp] = make_float2(accx, accy);
    }
    __syncthreads();

    // reduce 4 quarters, write fp16 S
    if (t < 256) {
        const int row2 = t >> 7, k = t & 127;
        const int kp2 = k >> 1, sel = k & 1;
        float s = 0.f;
        #pragma unroll
        for (int q = 0; q < 4; ++q) {
            float2 p2 = part[row2][q][kp2];
            s += sel ? p2.y : p2.x;
        }
        Sh[(i0 + row2)*KK + k] = (_Float16)s;
    }
}

// ---------- k_proj: MFMA GEMM C(2048x768) = S * W^T + b, row-masked ----------
__global__ __launch_bounds__(128) void k_proj(
    const _Float16* __restrict__ Sh,   // (2048,128)
    const _Float16* __restrict__ Wh,   // (768,128)
    const float* __restrict__ proj_b,  // (768)
    const int*   __restrict__ xatom,   // (2048)
    float* __restrict__ out)           // (2048,768)
{
    const int t    = threadIdx.x;
    const int lane = t & 63;
    const int wid  = t >> 6;
    const int bid  = blockIdx.x;
    const int r0   = ((bid & 63) << 5) + (wid << 4);
    const int d0   = (bid >> 6) << 6;

    const int lr = lane & 15;
    const int hi = lane >> 4;

    const _Float16* arow = Sh + (r0 + lr)*KK + hi*8;
    const _Float16* bcol = Wh + (d0 + lr)*KK + hi*8;

    f32x4 acc[4] = {};
    #pragma unroll
    for (int ks = 0; ks < 4; ++ks) {
        half8 a = *(const half8*)(arow + ks*32);
        #pragma unroll
        for (int c = 0; c < 4; ++c) {
            half8 b = *(const half8*)(bcol + c*16*KK + ks*32);
            acc[c] = __builtin_amdgcn_mfma_f32_16x16x32_f16(a, b, acc[c], 0, 0, 0);
        }
    }

    // C/D layout: col = lane&15, row = (lane>>4)*4 + reg
    #pragma unroll
    for (int reg = 0; reg < 4; ++reg) {
        const int row   = r0 + hi*4 + reg;
        const bool valid = (xatom[row] != 0);
        #pragma unroll
        for (int c = 0; c < 4; ++c) {
            const int col = d0 + c*16 + lr;
            const float v = acc[c][reg] + proj_b[col];
            out[row*DD + col] = valid ? v : 0.0f;
        }
    }
}

extern "C" void kernel_launch(void* const* d_in, const int* in_sizes, int n_in,
                              void* d_out, int out_size, void* d_ws, size_t ws_size,
                              hipStream_t stream) {
    const float* pos    = (const float*)d_in[0];
    const int*   xatom  = (const int*)  d_in[1];
    const float* means  = (const float*)d_in[2];
    const float* stds   = (const float*)d_in[3];
    const float* mul_w  = (const float*)d_in[4];
    const float* bias_w = (const float*)d_in[5];
    const float* proj_w = (const float*)d_in[6];
    const float* proj_b = (const float*)d_in[7];
    float* out = (float*)d_out;

    _Float16* Sh = (_Float16*)d_ws;                            // 512 KB
    _Float16* Wh = (_Float16*)((char*)d_ws + 512*1024);        // 192 KB
    _Float16* Gg = (_Float16*)((char*)d_ws + 704*1024);        // 48 KB

    const int BN = in_sizes[1];   // 2048

    k_prep <<<192, 256, 0, stream>>>(means, stds, proj_w, Gg, Wh);
    k_edges<<<BN/2, 512, 0, stream>>>(pos, xatom, mul_w, bias_w, Gg, Sh);
    k_proj <<<(BN/32)*(DD/64), 128, 0, stream>>>(Sh, Wh, proj_b, xatom, out);
}

// Round 5
// 23.002 us; speedup vs baseline: 1.2023x; 1.2023x over previous
//
#include <hip/hip_runtime.h>
#include <hip/hip_bf16.h>
#include <hip/hip_fp16.h>

// Graph3DBias: B=8, N=256, K=128, EMBED=768
// S[b,i,k] = sum_j mask_j * c_k * exp(-0.5*((y_bij-m_k)/s_k)^2),  y = mul*dist+bias
// out      = mask_i * (S @ W^T + b)
// 2 kernels: exp-based edges (trans-pipe bound, near floor) + fp16 MFMA proj
// with in-register W f32->fp16 conversion (k_prep eliminated).

#define NN 256
#define KK 128
#define DD 768

typedef _Float16 half8  __attribute__((ext_vector_type(8)));
typedef float    f32x4  __attribute__((ext_vector_type(4)));

// ---------------- Kernel 1: per-(b,i) gaussian accumulation ----------------
// grid = B*N blocks, 256 threads. Thread t: k = t&127, j-half = t>>7.
__global__ __launch_bounds__(256) void k_edges(
    const float* __restrict__ pos,     // (B,N,3)
    const int*   __restrict__ xatom,   // (B,N)
    const float* __restrict__ means,   // (K)
    const float* __restrict__ stds,    // (K)
    const float* __restrict__ mul_w,   // (1536)
    const float* __restrict__ bias_w,  // (1536)
    _Float16* __restrict__ Sh)         // (B*N, K) fp16
{
    const int bi = blockIdx.x;
    const int b  = bi >> 8;
    const int t  = threadIdx.x;
    const int base = b << 8;

    __shared__ __align__(16) float y_sh[NN];
    __shared__ float part[256];

    const int   ai  = xatom[bi];
    const float pix = pos[bi*3+0], piy = pos[bi*3+1], piz = pos[bi*3+2];

    {
        const int j  = t;
        const int aj = xatom[base + j];
        const float dx = pix - pos[(base+j)*3+0];
        const float dy = piy - pos[(base+j)*3+1];
        const float dz = piz - pos[(base+j)*3+2];
        const float dist = sqrtf(dx*dx + dy*dy + dz*dz);
        const int idx = ai*128 + aj;
        float y = mul_w[idx]*dist + bias_w[idx];
        if (aj == 0) y = 1e20f;   // padded j -> exp underflows to 0
        y_sh[j] = y;
    }
    __syncthreads();

    const int k    = t & 127;
    const int half = t >> 7;
    const float m   = means[k];
    const float s   = fabsf(stds[k]) + 0.8f;
    const float inv = 1.0f / s;
    const float w   = inv * 0.84932160f;     // sqrt(0.5*log2e)
    const float nm  = -m * w;
    const float c   = inv * 0.39894253f;     // 1/sqrt(2*3.14159)

    float a0=0.f, a1=0.f, a2=0.f, a3=0.f;
    const float4* yv = (const float4*)(y_sh + (half << 7));
    #pragma unroll
    for (int j4 = 0; j4 < 32; ++j4) {
        float4 y4 = yv[j4];                  // wave-uniform broadcast b128
        float d0 = fmaf(y4.x, w, nm); a0 += __builtin_amdgcn_exp2f(-(d0*d0));
        float d1 = fmaf(y4.y, w, nm); a1 += __builtin_amdgcn_exp2f(-(d1*d1));
        float d2 = fmaf(y4.z, w, nm); a2 += __builtin_amdgcn_exp2f(-(d2*d2));
        float d3 = fmaf(y4.w, w, nm); a3 += __builtin_amdgcn_exp2f(-(d3*d3));
    }
    part[t] = ((a0+a1)+(a2+a3)) * c;
    __syncthreads();

    if (t < 128)
        Sh[bi*KK + t] = (_Float16)(part[t] + part[t + 128]);
}

// ---------------- Kernel 2: MFMA projection GEMM -----------------
// C(2048x768) = S(fp16) * W^T(f32, converted in-register) + bias, row-masked.
// 768 blocks x 128 threads (2 waves); wave = 16-row x 64-col strip.
__global__ __launch_bounds__(128) void k_proj(
    const _Float16* __restrict__ Sh,   // (2048,128)
    const float* __restrict__ Wf,      // (768,128) f32
    const float* __restrict__ proj_b,  // (768)
    const int*   __restrict__ xatom,   // (2048)
    float* __restrict__ out)           // (2048,768)
{
    const int t    = threadIdx.x;
    const int lane = t & 63;
    const int wid  = t >> 6;
    const int bid  = blockIdx.x;
    const int r0   = ((bid & 63) << 5) + (wid << 4);  // 64 row-blocks of 32
    const int d0   = (bid >> 6) << 6;                 // 12 d-tiles of 64

    const int lr = lane & 15;
    const int hi = lane >> 4;

    const _Float16* arow = Sh + (r0 + lr)*KK + hi*8;
    const float*    bcol = Wf + (d0 + lr)*KK + hi*8;

    f32x4 acc[4] = {};
    #pragma unroll
    for (int ks = 0; ks < 4; ++ks) {
        half8 a = *(const half8*)(arow + ks*32);
        #pragma unroll
        for (int c = 0; c < 4; ++c) {
            const float* bp = bcol + c*16*KK + ks*32;
            float4 b0 = *(const float4*)(bp);
            float4 b1 = *(const float4*)(bp + 4);
            half8 bh;
            bh[0]=(_Float16)b0.x; bh[1]=(_Float16)b0.y;
            bh[2]=(_Float16)b0.z; bh[3]=(_Float16)b0.w;
            bh[4]=(_Float16)b1.x; bh[5]=(_Float16)b1.y;
            bh[6]=(_Float16)b1.z; bh[7]=(_Float16)b1.w;
            acc[c] = __builtin_amdgcn_mfma_f32_16x16x32_f16(a, bh, acc[c], 0, 0, 0);
        }
    }

    // C/D layout (verified m89): col = lane&15, row = (lane>>4)*4 + reg
    #pragma unroll
    for (int reg = 0; reg < 4; ++reg) {
        const int row   = r0 + hi*4 + reg;
        const bool valid = (xatom[row] != 0);
        #pragma unroll
        for (int c = 0; c < 4; ++c) {
            const int col = d0 + c*16 + lr;
            const float v = acc[c][reg] + proj_b[col];
            out[row*DD + col] = valid ? v : 0.0f;
        }
    }
}

extern "C" void kernel_launch(void* const* d_in, const int* in_sizes, int n_in,
                              void* d_out, int out_size, void* d_ws, size_t ws_size,
                              hipStream_t stream) {
    const float* pos    = (const float*)d_in[0];
    const int*   xatom  = (const int*)  d_in[1];
    const float* means  = (const float*)d_in[2];
    const float* stds   = (const float*)d_in[3];
    const float* mul_w  = (const float*)d_in[4];
    const float* bias_w = (const float*)d_in[5];
    const float* proj_w = (const float*)d_in[6];
    const float* proj_b = (const float*)d_in[7];
    float* out = (float*)d_out;

    _Float16* Sh = (_Float16*)d_ws;    // 512 KB scratch

    const int BN = in_sizes[1];        // B*N = 2048

    k_edges<<<BN, 256, 0, stream>>>(pos, xatom, means, stds, mul_w, bias_w, Sh);
    k_proj <<<(BN/32)*(DD/64), 128, 0, stream>>>(Sh, proj_w, proj_b, xatom, out);
}